// Round 1
// 25939.233 us; speedup vs baseline: 1.2154x; 1.2154x over previous
//
#include <hip/hip_runtime.h>
#include <hip/hip_fp16.h>
#include <math.h>

// ---------------------------------------------------------------------------
// V projection precompute (fp32 SGEMM, fp16 out): out[b][h][m][d], row-major [m][d]
// grid: jt(8) + 8*(mt(8) + 8*b(128)); block 256 = 16x16 threads, 4x4 out each
// ---------------------------------------------------------------------------
__global__ __launch_bounds__(256) void kv_proj(
    const float* __restrict__ mem, const float* __restrict__ W,
    const float* __restrict__ bias, __half* __restrict__ outp) {
  __shared__ float As[32][68];
  __shared__ float Bs[32][68];
  int gid = blockIdx.x;
  int jt = gid & 7, mt = (gid >> 3) & 7, b = gid >> 6;
  int t = threadIdx.x;
  int lm = t >> 2;
  int kq = (t & 3) * 8;
  int tx = t & 15, ty = t >> 4;
  float acc[4][4];
  #pragma unroll
  for (int r = 0; r < 4; ++r)
    #pragma unroll
    for (int c = 0; c < 4; ++c) acc[r][c] = 0.f;
  const float* Arow = mem + (size_t)(mt * 64 + lm) * 65536 + (size_t)b * 512 + kq;
  const float* Brow = W + (size_t)(jt * 64 + lm) * 512 + kq;
  for (int k0 = 0; k0 < 512; k0 += 32) {
    float4 a0 = *(const float4*)(Arow + k0);
    float4 a1 = *(const float4*)(Arow + k0 + 4);
    float4 b0 = *(const float4*)(Brow + k0);
    float4 b1 = *(const float4*)(Brow + k0 + 4);
    As[kq + 0][lm] = a0.x; As[kq + 1][lm] = a0.y; As[kq + 2][lm] = a0.z; As[kq + 3][lm] = a0.w;
    As[kq + 4][lm] = a1.x; As[kq + 5][lm] = a1.y; As[kq + 6][lm] = a1.z; As[kq + 7][lm] = a1.w;
    Bs[kq + 0][lm] = b0.x; Bs[kq + 1][lm] = b0.y; Bs[kq + 2][lm] = b0.z; Bs[kq + 3][lm] = b0.w;
    Bs[kq + 4][lm] = b1.x; Bs[kq + 5][lm] = b1.y; Bs[kq + 6][lm] = b1.z; Bs[kq + 7][lm] = b1.w;
    __syncthreads();
    #pragma unroll
    for (int k = 0; k < 32; ++k) {
      float4 av = *(const float4*)&As[k][ty * 4];
      float4 bv = *(const float4*)&Bs[k][tx * 4];
      float ar[4] = {av.x, av.y, av.z, av.w};
      float br[4] = {bv.x, bv.y, bv.z, bv.w};
      #pragma unroll
      for (int r = 0; r < 4; ++r)
        #pragma unroll
        for (int c = 0; c < 4; ++c) acc[r][c] = fmaf(ar[r], br[c], acc[r][c]);
    }
    __syncthreads();
  }
  float4 bb = *(const float4*)(bias + jt * 64 + tx * 4);
  #pragma unroll
  for (int r = 0; r < 4; ++r) {
    int m = mt * 64 + ty * 4 + r;
    __half2 p0 = __floats2half2_rn(acc[r][0] + bb.x, acc[r][1] + bb.y);
    __half2 p1 = __floats2half2_rn(acc[r][2] + bb.z, acc[r][3] + bb.w);
    union { uint2 u; __half2 h[2]; } W2;
    W2.h[0] = p0; W2.h[1] = p1;
    *(uint2*)(outp + (((size_t)b * 8 + jt) * 512 + m) * 64 + tx * 4) = W2.u;
  }
}

// ---------------------------------------------------------------------------
// K projection, TRANSPOSED fp16 output: out[b][h][d][m]  (d = head-local 0..63)
// ---------------------------------------------------------------------------
__global__ __launch_bounds__(256) void kv_projT(
    const float* __restrict__ mem, const float* __restrict__ W,
    const float* __restrict__ bias, __half* __restrict__ outp) {
  __shared__ float As[32][68];
  __shared__ float Bs[32][68];
  int gid = blockIdx.x;
  int jt = gid & 7, mt = (gid >> 3) & 7, b = gid >> 6;
  int t = threadIdx.x;
  int lm = t >> 2;
  int kq = (t & 3) * 8;
  int tx = t & 15, ty = t >> 4;
  float acc[4][4];
  #pragma unroll
  for (int r = 0; r < 4; ++r)
    #pragma unroll
    for (int c = 0; c < 4; ++c) acc[r][c] = 0.f;
  const float* Arow = mem + (size_t)(mt * 64 + lm) * 65536 + (size_t)b * 512 + kq;
  const float* Brow = W + (size_t)(jt * 64 + lm) * 512 + kq;
  for (int k0 = 0; k0 < 512; k0 += 32) {
    float4 a0 = *(const float4*)(Arow + k0);
    float4 a1 = *(const float4*)(Arow + k0 + 4);
    float4 b0 = *(const float4*)(Brow + k0);
    float4 b1 = *(const float4*)(Brow + k0 + 4);
    As[kq + 0][lm] = a0.x; As[kq + 1][lm] = a0.y; As[kq + 2][lm] = a0.z; As[kq + 3][lm] = a0.w;
    As[kq + 4][lm] = a1.x; As[kq + 5][lm] = a1.y; As[kq + 6][lm] = a1.z; As[kq + 7][lm] = a1.w;
    Bs[kq + 0][lm] = b0.x; Bs[kq + 1][lm] = b0.y; Bs[kq + 2][lm] = b0.z; Bs[kq + 3][lm] = b0.w;
    Bs[kq + 4][lm] = b1.x; Bs[kq + 5][lm] = b1.y; Bs[kq + 6][lm] = b1.z; Bs[kq + 7][lm] = b1.w;
    __syncthreads();
    #pragma unroll
    for (int k = 0; k < 32; ++k) {
      float4 av = *(const float4*)&As[k][ty * 4];
      float4 bv = *(const float4*)&Bs[k][tx * 4];
      float ar[4] = {av.x, av.y, av.z, av.w};
      float br[4] = {bv.x, bv.y, bv.z, bv.w};
      #pragma unroll
      for (int r = 0; r < 4; ++r)
        #pragma unroll
        for (int c = 0; c < 4; ++c) acc[r][c] = fmaf(ar[r], br[c], acc[r][c]);
    }
    __syncthreads();
  }
  float4 bb = *(const float4*)(bias + jt * 64 + tx * 4);
  float bc[4] = {bb.x, bb.y, bb.z, bb.w};
  #pragma unroll
  for (int r = 0; r < 4; ++r) {
    int m = mt * 64 + ty * 4 + r;
    #pragma unroll
    for (int c = 0; c < 4; ++c) {
      int d = tx * 4 + c;  // head-local dim
      outp[((size_t)(b * 8 + jt) * 64 + d) * 512 + m] = __float2half_rn(acc[r][c] + bc[c]);
    }
  }
}

// ---------------------------------------------------------------------------
// E2 = emb @ Wq[:, :512]^T + bq   -> [1000][512] fp32 (embedding half of q-proj)
// grid 128: jt = gid & 7 (64 j each), mt = gid >> 3 (16 tiles of 64 v, guarded)
// ---------------------------------------------------------------------------
__global__ __launch_bounds__(256) void e2_kernel(
    const float* __restrict__ emb, const float* __restrict__ Wq,
    const float* __restrict__ bq, float* __restrict__ E2) {
  __shared__ float As[32][68];
  __shared__ float Bs[32][68];
  int gid = blockIdx.x;
  int jt = gid & 7, mt = gid >> 3;
  int t = threadIdx.x;
  int lm = t >> 2;
  int kq = (t & 3) * 8;
  int tx = t & 15, ty = t >> 4;
  float acc[4][4];
  #pragma unroll
  for (int r = 0; r < 4; ++r)
    #pragma unroll
    for (int c = 0; c < 4; ++c) acc[r][c] = 0.f;
  int v = mt * 64 + lm;
  bool aok = v < 1000;
  const float* Arow = emb + (size_t)v * 512 + kq;
  const float* Brow = Wq + (size_t)(jt * 64 + lm) * 1024 + kq;  // emb-half cols [0,512)
  for (int k0 = 0; k0 < 512; k0 += 32) {
    float4 a0, a1;
    if (aok) {
      a0 = *(const float4*)(Arow + k0);
      a1 = *(const float4*)(Arow + k0 + 4);
    } else {
      a0 = make_float4(0.f, 0.f, 0.f, 0.f);
      a1 = make_float4(0.f, 0.f, 0.f, 0.f);
    }
    float4 b0 = *(const float4*)(Brow + k0);
    float4 b1 = *(const float4*)(Brow + k0 + 4);
    As[kq + 0][lm] = a0.x; As[kq + 1][lm] = a0.y; As[kq + 2][lm] = a0.z; As[kq + 3][lm] = a0.w;
    As[kq + 4][lm] = a1.x; As[kq + 5][lm] = a1.y; As[kq + 6][lm] = a1.z; As[kq + 7][lm] = a1.w;
    Bs[kq + 0][lm] = b0.x; Bs[kq + 1][lm] = b0.y; Bs[kq + 2][lm] = b0.z; Bs[kq + 3][lm] = b0.w;
    Bs[kq + 4][lm] = b1.x; Bs[kq + 5][lm] = b1.y; Bs[kq + 6][lm] = b1.z; Bs[kq + 7][lm] = b1.w;
    __syncthreads();
    #pragma unroll
    for (int k = 0; k < 32; ++k) {
      float4 av = *(const float4*)&As[k][ty * 4];
      float4 bv = *(const float4*)&Bs[k][tx * 4];
      float ar[4] = {av.x, av.y, av.z, av.w};
      float br[4] = {bv.x, bv.y, bv.z, bv.w};
      #pragma unroll
      for (int r = 0; r < 4; ++r)
        #pragma unroll
        for (int c = 0; c < 4; ++c) acc[r][c] = fmaf(ar[r], br[c], acc[r][c]);
    }
    __syncthreads();
  }
  float4 bb = *(const float4*)(bq + jt * 64 + tx * 4);
  float bc[4] = {bb.x, bb.y, bb.z, bb.w};
  #pragma unroll
  for (int r = 0; r < 4; ++r) {
    int vv = mt * 64 + ty * 4 + r;
    if (vv < 1000) {
      #pragma unroll
      for (int c = 0; c < 4; ++c)
        E2[(size_t)vv * 512 + jt * 64 + tx * 4 + c] = acc[r][c] + bc[c];
    }
  }
}

// ---------------------------------------------------------------------------
__global__ __launch_bounds__(256) void init_kernel(float* __restrict__ h0,
                                                   float* __restrict__ qh,
                                                   unsigned long long* __restrict__ packed) {
  int t = threadIdx.x + blockIdx.x * blockDim.x;
  for (int i = t; i < 128 * 512; i += blockDim.x * gridDim.x) {
    h0[i] = 0.f;
    qh[i] = 0.f;  // h_prev = 0 at t=0 -> hidden half of q is 0
  }
  if (t < 128) packed[t] = (0x80000000ull << 32) | 0xFFFFFFFFull;  // val 0.0, idx 0
}

// ---------------------------------------------------------------------------
// Fused attention (q-proj hoisted out). One block per (b, head).
//   q = E2[tok] + qh  (E2 includes bq; qh = h_prev @ Wq_h^T from prev logits)
//   K^T fp16 [64][512] fully-coalesced half2 stream; V fp16 [512][64]
// ---------------------------------------------------------------------------
__global__ __launch_bounds__(256) void attn_fused(
    const __half* __restrict__ kpT, const __half* __restrict__ vp,
    const float* __restrict__ E2, const float* __restrict__ qh,
    const unsigned long long* __restrict__ packed,
    float* __restrict__ ctx, float* __restrict__ att_buf) {
  int b = blockIdx.x >> 3, hd = blockIdx.x & 7;
  __shared__ float qs[64];
  __shared__ float att[512];
  __shared__ __align__(16) float red[16][68];
  __shared__ float rmax[4], rsum[4];
  __shared__ int tok_s;
  int t = threadIdx.x;
  if (t == 0) tok_s = (int)(0xFFFFFFFFu - (unsigned int)(packed[b] & 0xFFFFFFFFull));
  __syncthreads();
  int tok = tok_s;
  if (t < 64)
    qs[t] = qh[(size_t)b * 512 + hd * 64 + t] + E2[(size_t)tok * 512 + hd * 64 + t];
  __syncthreads();

  // --- scores: thread t owns m = 2t, 2t+1; K^T stream fully coalesced ---
  const __half* Kb = kpT + (size_t)(b * 8 + hd) * 32768;  // [64][512]
  float s0 = 0.f, s1 = 0.f;
  {
    int m2 = 2 * t;
    #pragma unroll 16
    for (int d = 0; d < 64; ++d) {
      __half2 kk = *(const __half2*)(Kb + (size_t)d * 512 + m2);
      float2 kf = __half22float2(kk);
      float qd = qs[d];
      s0 = fmaf(qd, kf.x, s0);
      s1 = fmaf(qd, kf.y, s1);
    }
    s0 *= 0.125f;  // 1/sqrt(64)
    s1 *= 0.125f;
  }
  // --- softmax over 512 ---
  float mx = fmaxf(s0, s1);
  #pragma unroll
  for (int o = 32; o > 0; o >>= 1) mx = fmaxf(mx, __shfl_xor(mx, o));
  if ((t & 63) == 0) rmax[t >> 6] = mx;
  __syncthreads();
  mx = fmaxf(fmaxf(rmax[0], rmax[1]), fmaxf(rmax[2], rmax[3]));
  float e0 = expf(s0 - mx), e1 = expf(s1 - mx);
  float sm = e0 + e1;
  #pragma unroll
  for (int o = 32; o > 0; o >>= 1) sm += __shfl_xor(sm, o);
  if ((t & 63) == 0) rsum[t >> 6] = sm;
  __syncthreads();
  sm = rsum[0] + rsum[1] + rsum[2] + rsum[3];
  float inv = 1.f / sm;
  float a0 = e0 * inv, a1 = e1 * inv;
  att[2 * t] = a0;
  att[2 * t + 1] = a1;
  *(float2*)(att_buf + (size_t)(b * 8 + hd) * 512 + 2 * t) = make_float2(a0, a1);
  __syncthreads();

  // --- ctx: thread = (row-group g = t>>4, d-slice = (t&15)*4) ---
  const __half* Vb = vp + (size_t)(b * 8 + hd) * 32768;  // [512][64]
  {
    int dsl = (t & 15) * 4, g = t >> 4;
    float c0 = 0.f, c1 = 0.f, c2 = 0.f, c3 = 0.f;
    #pragma unroll 8
    for (int m = g; m < 512; m += 16) {
      union { uint2 u; __half2 h[2]; } U;
      U.u = *(const uint2*)(Vb + (size_t)m * 64 + dsl);
      float2 f01 = __half22float2(U.h[0]);
      float2 f23 = __half22float2(U.h[1]);
      float am = att[m];
      c0 = fmaf(am, f01.x, c0);
      c1 = fmaf(am, f01.y, c1);
      c2 = fmaf(am, f23.x, c2);
      c3 = fmaf(am, f23.y, c3);
    }
    red[g][dsl + 0] = c0;
    red[g][dsl + 1] = c1;
    red[g][dsl + 2] = c2;
    red[g][dsl + 3] = c3;
  }
  __syncthreads();
  if (t < 64) {
    float cc = 0.f;
    #pragma unroll
    for (int g2 = 0; g2 < 16; ++g2) cc += red[g2][t];
    ctx[(size_t)b * 512 + hd * 64 + t] = cc;
  }
}

// ---------------------------------------------------------------------------
// GRU + hiddens-out; extra blocks: scores-out (mean over heads) + packed reset
// grid 320: [0,256) GRU (bt16 x jt16), [256,320) scores
// ---------------------------------------------------------------------------
__global__ __launch_bounds__(256) void gru_kernel(
    const float* __restrict__ W_ih, const float* __restrict__ W_hh,
    const float* __restrict__ b_ih, const float* __restrict__ b_hh,
    const float* __restrict__ ctx, const float* __restrict__ h_prev,
    float* __restrict__ h_new, const float* __restrict__ att_buf,
    const int* __restrict__ lens, float* __restrict__ out_hid,
    float* __restrict__ out_sc, unsigned long long* __restrict__ packed,
    int step) {
  __shared__ float cs[8][512];
  __shared__ float hs[8][512];
  int bi = blockIdx.x;
  int t = threadIdx.x;
  if (bi >= 256) {
    int sb = bi - 256;  // 0..63
    if (sb == 0 && t < 128) packed[t] = 0ull;  // reset for this step's logits atomics
    #pragma unroll
    for (int i = 0; i < 4; ++i) {
      int flat = sb * 1024 + i * 256 + t;  // over b*512+m
      int bb = flat >> 9, m = flat & 511;
      float sum = 0.f;
      #pragma unroll
      for (int h = 0; h < 8; ++h) sum += att_buf[(size_t)(bb * 8 + h) * 512 + m];
      float val = sum * 0.125f;
      out_sc[(size_t)step * 65536 + flat] = (step < lens[bb]) ? val : 0.f;
    }
    return;
  }
  int bt = bi >> 4, jt = bi & 15;
  #pragma unroll
  for (int i = 0; i < 16; ++i) {
    int flat = i * 256 + t;
    int lb = flat >> 9, k = flat & 511;
    cs[lb][k] = ctx[(size_t)(bt * 8 + lb) * 512 + k];
    hs[lb][k] = h_prev[(size_t)(bt * 8 + lb) * 512 + k];
  }
  __syncthreads();
  int lb = t >> 5, j = (jt << 5) + (t & 31);
  int b = bt * 8 + lb;
  float air = b_ih[j], aiz = b_ih[512 + j], ain = b_ih[1024 + j];
  float ahr = b_hh[j], ahz = b_hh[512 + j], ahn = b_hh[1024 + j];
  const float* c = cs[lb];
  const float* hh = hs[lb];
  const float* wi0 = W_ih + (size_t)j * 512;
  const float* wi1 = W_ih + (size_t)(512 + j) * 512;
  const float* wi2 = W_ih + (size_t)(1024 + j) * 512;
  const float* wh0 = W_hh + (size_t)j * 512;
  const float* wh1 = W_hh + (size_t)(512 + j) * 512;
  const float* wh2 = W_hh + (size_t)(1024 + j) * 512;
  #pragma unroll 2
  for (int k = 0; k < 512; k += 4) {
    float4 wa = *(const float4*)(wi0 + k);
    float4 wb = *(const float4*)(wi1 + k);
    float4 wc = *(const float4*)(wi2 + k);
    float4 wd = *(const float4*)(wh0 + k);
    float4 we = *(const float4*)(wh1 + k);
    float4 wf = *(const float4*)(wh2 + k);
    float c0 = c[k], c1 = c[k + 1], c2 = c[k + 2], c3 = c[k + 3];
    float h0 = hh[k], h1 = hh[k + 1], h2 = hh[k + 2], h3 = hh[k + 3];
    air = fmaf(c0, wa.x, air); air = fmaf(c1, wa.y, air); air = fmaf(c2, wa.z, air); air = fmaf(c3, wa.w, air);
    aiz = fmaf(c0, wb.x, aiz); aiz = fmaf(c1, wb.y, aiz); aiz = fmaf(c2, wb.z, aiz); aiz = fmaf(c3, wb.w, aiz);
    ain = fmaf(c0, wc.x, ain); ain = fmaf(c1, wc.y, ain); ain = fmaf(c2, wc.z, ain); ain = fmaf(c3, wc.w, ain);
    ahr = fmaf(h0, wd.x, ahr); ahr = fmaf(h1, wd.y, ahr); ahr = fmaf(h2, wd.z, ahr); ahr = fmaf(h3, wd.w, ahr);
    ahz = fmaf(h0, we.x, ahz); ahz = fmaf(h1, we.y, ahz); ahz = fmaf(h2, we.z, ahz); ahz = fmaf(h3, we.w, ahz);
    ahn = fmaf(h0, wf.x, ahn); ahn = fmaf(h1, wf.y, ahn); ahn = fmaf(h2, wf.z, ahn); ahn = fmaf(h3, wf.w, ahn);
  }
  float r = 1.f / (1.f + expf(-(air + ahr)));
  float z = 1.f / (1.f + expf(-(aiz + ahz)));
  float n = tanhf(fmaf(r, ahn, ain));
  float hp = hh[j];
  float hv = (1.f - z) * n + z * hp;
  h_new[(size_t)b * 512 + j] = hv;
  out_hid[(size_t)step * 65536 + (size_t)b * 512 + j] = (step < lens[b]) ? hv : 0.f;
}

// ---------------------------------------------------------------------------
// Logits + outputs-out + argmax (packed u64 atomicMax) + qh for NEXT step
// grid 256: bt(16) x vt(16, 64 v each); block 256: 8b x 32v x 2r
// ---------------------------------------------------------------------------
__global__ __launch_bounds__(256) void logits_kernel(
    const float* __restrict__ Wfc, const float* __restrict__ bfc,
    const float* __restrict__ h_new, const int* __restrict__ lens,
    float* __restrict__ out_o, unsigned long long* __restrict__ packed,
    const float* __restrict__ Wq, float* __restrict__ qh, int step) {
  __shared__ float hs[8][512];
  int bi = blockIdx.x;
  int t = threadIdx.x;
  int bt = bi >> 4, vt = bi & 15;
  #pragma unroll
  for (int i = 0; i < 16; ++i) {
    int flat = i * 256 + t;
    int lb = flat >> 9, k = flat & 511;
    hs[lb][k] = h_new[(size_t)(bt * 8 + lb) * 512 + k];
  }
  __syncthreads();
  int lb = t >> 5, vv = t & 31;
  int b = bt * 8 + lb;
  const float* a = hs[lb];
  int run = step < lens[b];
  float bestv = -1e30f;
  int besti = 0;
  #pragma unroll
  for (int r = 0; r < 2; ++r) {
    int v = vt * 64 + r * 32 + vv;
    if (v < 1000) {
      float acc = bfc[v];
      const float* wrow = Wfc + (size_t)v * 512;
      #pragma unroll 4
      for (int k = 0; k < 512; k += 4) {
        float4 w = *(const float4*)(wrow + k);
        acc = fmaf(a[k + 0], w.x, acc);
        acc = fmaf(a[k + 1], w.y, acc);
        acc = fmaf(a[k + 2], w.z, acc);
        acc = fmaf(a[k + 3], w.w, acc);
      }
      out_o[(size_t)step * 128000 + (size_t)b * 1000 + v] = run ? acc : 0.f;
      if (acc > bestv) { bestv = acc; besti = v; }  // strict > keeps smallest v
    }
  }
  #pragma unroll
  for (int o = 16; o > 0; o >>= 1) {
    float ov = __shfl_xor(bestv, o);
    int oi = __shfl_xor(besti, o);
    if (ov > bestv || (ov == bestv && oi < besti)) { bestv = ov; besti = oi; }
  }
  if (vv == 0) {
    unsigned int fb = __float_as_uint(bestv);
    fb = (fb & 0x80000000u) ? ~fb : (fb | 0x80000000u);
    unsigned long long key =
        ((unsigned long long)fb << 32) | (unsigned long long)(0xFFFFFFFFu - (unsigned int)besti);
    atomicMax(packed + b, key);
  }

  // --- qh for next step: qh[b][j] = h_new[b] . Wq[j, 512:1024] ---
  // thread = (lb = t>>5 in [0,8), jq = vt*32 + (t&31)); vt covers all 512 j
  {
    int jq = vt * 32 + (t & 31);
    const float* wrow = Wq + (size_t)jq * 1024 + 512;  // hidden-half cols
    float acc = 0.f;
    #pragma unroll 4
    for (int k = 0; k < 512; k += 4) {
      float4 w = *(const float4*)(wrow + k);
      acc = fmaf(a[k + 0], w.x, acc);
      acc = fmaf(a[k + 1], w.y, acc);
      acc = fmaf(a[k + 2], w.z, acc);
      acc = fmaf(a[k + 3], w.w, acc);
    }
    qh[(size_t)b * 512 + jq] = acc;
  }
}

// ---------------------------------------------------------------------------
extern "C" void kernel_launch(void* const* d_in, const int* in_sizes, int n_in,
                              void* d_out, int out_size, void* d_ws, size_t ws_size,
                              hipStream_t stream) {
  const float* memory = (const float*)d_in[0];
  const float* emb    = (const float*)d_in[1];
  const float* Wq     = (const float*)d_in[2];
  const float* bq     = (const float*)d_in[3];
  const float* Wk     = (const float*)d_in[4];
  const float* bk     = (const float*)d_in[5];
  const float* Wv     = (const float*)d_in[6];
  const float* bv     = (const float*)d_in[7];
  const float* W_ih   = (const float*)d_in[8];
  const float* W_hh   = (const float*)d_in[9];
  const float* b_ih   = (const float*)d_in[10];
  const float* b_hh   = (const float*)d_in[11];
  const float* Wfc    = (const float*)d_in[12];
  const float* bfc    = (const float*)d_in[13];
  const int* lens     = (const int*)d_in[14];

  __half* kpT = (__half*)d_ws;               // 33,554,432 halfs  [b][h][d][m]
  __half* vp  = kpT + 33554432;              // 33,554,432 halfs  [b][h][m][d]
  float* ctx     = (float*)(vp + 33554432);  // 65,536 f
  float* h0      = ctx + 65536;              // 65,536 f
  float* h1      = h0 + 65536;               // 65,536 f
  float* qh      = h1 + 65536;               // 65,536 f
  float* E2      = qh + 65536;               // 512,000 f (1000 x 512, includes bq)
  float* att_buf = E2 + 512000;              // 524,288 f
  unsigned long long* packed = (unsigned long long*)(att_buf + 524288);  // 128 u64

  float* out   = (float*)d_out;
  float* out_o = out;                  // 160*128*1000
  float* out_h = out + 20480000;       // 160*128*512
  float* out_s = out_h + 10485760;     // 160*128*512

  kv_projT<<<8192, 256, 0, stream>>>(memory, Wk, bk, kpT);
  kv_proj<<<8192, 256, 0, stream>>>(memory, Wv, bv, vp);
  e2_kernel<<<128, 256, 0, stream>>>(emb, Wq, bq, E2);
  init_kernel<<<64, 256, 0, stream>>>(h0, qh, packed);

  for (int t = 0; t < 160; ++t) {
    float* hp = (t & 1) ? h1 : h0;
    float* hn = (t & 1) ? h0 : h1;
    attn_fused<<<1024, 256, 0, stream>>>(kpT, vp, E2, qh, packed, ctx, att_buf);
    gru_kernel<<<320, 256, 0, stream>>>(W_ih, W_hh, b_ih, b_hh, ctx, hp, hn,
                                        att_buf, lens, out_h, out_s, packed, t);
    logits_kernel<<<256, 256, 0, stream>>>(Wfc, bfc, hn, lens, out_o, packed, Wq, qh, t);
  }
}